// Round 1
// baseline (302.666 us; speedup 1.0000x reference)
//
#include <hip/hip_runtime.h>

// Hierarchical softmax loss: B=128, PRED_SIZE=128+128*128=16512, BATCH=4096.
// loss = mean_s [ LSE(pred[s,0:128]) - pred[s,parent]
//               + LSE(pred[s,128+parent*128 : +128]) - pred[s,128+parent*128+child] ]
// parent = target/128, child = target%128.

#define BRANCH 128
#define PRED_SIZE 16512
#define BATCH 4096

constexpr int SAMPLES_PER_WAVE = 4;
constexpr int WAVES_PER_BLOCK  = 4;
constexpr int SAMPLES_PER_BLOCK = SAMPLES_PER_WAVE * WAVES_PER_BLOCK;  // 16
constexpr int GRID = BATCH / SAMPLES_PER_BLOCK;                        // 256

__global__ __launch_bounds__(256)
void hsm_loss_kernel(const float* __restrict__ pred,
                     const int* __restrict__ targets,
                     float* __restrict__ out) {
    const int lane = threadIdx.x & 63;
    const int wave = threadIdx.x >> 6;
    const int s0 = blockIdx.x * SAMPLES_PER_BLOCK + wave * SAMPLES_PER_WAVE;

    float wave_sum = 0.0f;

    #pragma unroll
    for (int i = 0; i < SAMPLES_PER_WAVE; ++i) {
        const int s = s0 + i;
        const float* base = pred + (size_t)s * PRED_SIZE;
        const int t = targets[s];
        const int parent = t >> 7;     // t / 128
        const int child  = t & 127;    // t % 128

        // Root segment: 128 floats; child segment: 128 floats at 128+parent*128.
        const float2 r = *(const float2*)(base + lane * 2);
        const float2 c = *(const float2*)(base + BRANCH + parent * BRANCH + lane * 2);

        // Max reduction (both levels in one shuffle chain).
        float m1 = fmaxf(r.x, r.y);
        float m2 = fmaxf(c.x, c.y);
        #pragma unroll
        for (int off = 1; off < 64; off <<= 1) {
            m1 = fmaxf(m1, __shfl_xor(m1, off, 64));
            m2 = fmaxf(m2, __shfl_xor(m2, off, 64));
        }

        // Exp-sum reduction.
        float e1 = __expf(r.x - m1) + __expf(r.y - m1);
        float e2 = __expf(c.x - m2) + __expf(c.y - m2);
        #pragma unroll
        for (int off = 1; off < 64; off <<= 1) {
            e1 += __shfl_xor(e1, off, 64);
            e2 += __shfl_xor(e2, off, 64);
        }

        if (lane == 0) {
            const float t1 = base[parent];
            const float t2 = base[BRANCH + parent * BRANCH + child];
            wave_sum += (m1 + __logf(e1) - t1) + (m2 + __logf(e2) - t2);
        }
    }

    __shared__ float wsum[WAVES_PER_BLOCK];
    if (lane == 0) wsum[wave] = wave_sum;
    __syncthreads();
    if (threadIdx.x == 0) {
        float bs = wsum[0] + wsum[1] + wsum[2] + wsum[3];
        atomicAdd(out, bs * (1.0f / BATCH));
    }
}

extern "C" void kernel_launch(void* const* d_in, const int* in_sizes, int n_in,
                              void* d_out, int out_size, void* d_ws, size_t ws_size,
                              hipStream_t stream) {
    const float* pred = (const float*)d_in[0];
    const int* targets = (const int*)d_in[1];
    float* out = (float*)d_out;

    // d_out is poisoned (0xAA) before every timed launch; zero it in-stream.
    hipMemsetAsync(out, 0, sizeof(float), stream);
    hsm_loss_kernel<<<GRID, 256, 0, stream>>>(pred, targets, out);
}